// Round 8
// baseline (67.371 us; speedup 1.0000x reference)
//
#include <hip/hip_runtime.h>
#include <hip/hip_bf16.h>
#include <math.h>

// Problem: x, y fp32 [NT=5000, 512, 16] -> scalar
//   per column c (of 8192): sxx=sum x^2, syy=sum y^2, sxy=sum x*y, mx=max|x|
//   cc = -0.001*sxy/((sqrt(sxx)+1e-10)*(sqrt(syy)+1e-10)); out = sum(cc where mx>0)

#define NT       5000
#define NROW_F   8192          // floats per time row (512*16)
#define NCOL     8192
#define NCOL4    2048
#define NCHUNK   64            // 8 col-tiles * 64 = 512 blocks = 2/CU (R6 best)
#define NCBLK    128           // combine grid

typedef __attribute__((address_space(3))) void lds_void;
typedef const __attribute__((address_space(1))) void gm_void;

// ---------------------------------------------------------------------------
// Phase 1 (R4/R6-proven config — ~6.05 TB/s delivered, 96% of float4-copy
// ceiling): wave-independent global_load_lds pipeline.
// grid = (8 col-tiles, 64 chunks); block = 256 (4 waves), LDS 64KB ->
// 2 blocks/CU = 8 waves/CU. Per 4-row tile: 8 x global_load_lds_dwordx4
// (1KB each) fire-and-forget, counted s_waitcnt vmcnt(8) (never 0 mid-loop),
// ds_read_b128 consume. No __syncthreads in the loop.
// Also zeroes the combine-completion counter (graph-replay-safe init).
// ---------------------------------------------------------------------------
__global__ __launch_bounds__(256) void ncc_partial(const float* __restrict__ xg,
                                                   const float* __restrict__ yg,
                                                   float4* __restrict__ ws,
                                                   int* __restrict__ counter,
                                                   int clen, int T) {
    __shared__ float4 BA[4][4][2][64];
    __shared__ float4 BB[4][4][2][64];

    const int tid  = threadIdx.x;
    const int w    = tid >> 6;
    const int lane = tid & 63;
    const int bx   = blockIdx.x;        // 0..7 col-tile (1024 floats each)
    const int ch   = blockIdx.y;
    const int n0   = ch * clen;
    int n1 = n0 + clen; if (n1 > NT) n1 = NT;

    if (bx == 0 && ch == 0 && tid == 0) *counter = 0;   // init for phase 2

    const int colf = bx * 1024 + tid * 4;   // first float column of this thread

    float4 sxx = make_float4(0.f, 0.f, 0.f, 0.f);
    float4 syy = make_float4(0.f, 0.f, 0.f, 0.f);
    float4 sxy = make_float4(0.f, 0.f, 0.f, 0.f);
    float4 mx  = make_float4(0.f, 0.f, 0.f, 0.f);

#define ACC4(a, b)                                                      \
    sxx.x = fmaf(a.x, a.x, sxx.x); sxx.y = fmaf(a.y, a.y, sxx.y);       \
    sxx.z = fmaf(a.z, a.z, sxx.z); sxx.w = fmaf(a.w, a.w, sxx.w);       \
    syy.x = fmaf(b.x, b.x, syy.x); syy.y = fmaf(b.y, b.y, syy.y);       \
    syy.z = fmaf(b.z, b.z, syy.z); syy.w = fmaf(b.w, b.w, syy.w);       \
    sxy.x = fmaf(a.x, b.x, sxy.x); sxy.y = fmaf(a.y, b.y, sxy.y);       \
    sxy.z = fmaf(a.z, b.z, sxy.z); sxy.w = fmaf(a.w, b.w, sxy.w);       \
    mx.x = fmaxf(mx.x, fabsf(a.x)); mx.y = fmaxf(mx.y, fabsf(a.y));     \
    mx.z = fmaxf(mx.z, fabsf(a.z)); mx.w = fmaxf(mx.w, fabsf(a.w))

#define ISSUE(BUF, t)                                                         \
    {                                                                         \
        _Pragma("unroll")                                                     \
        for (int r = 0; r < 4; ++r) {                                         \
            int n = n0 + (t) * 4 + r;                                         \
            if (n > NT - 1) n = NT - 1;                                       \
            const float* px = xg + (size_t)n * NROW_F + colf;                 \
            const float* py = yg + (size_t)n * NROW_F + colf;                 \
            __builtin_amdgcn_global_load_lds((gm_void*)px,                    \
                (lds_void*)&BUF[w][r][0][0], 16, 0, 0);                       \
            __builtin_amdgcn_global_load_lds((gm_void*)py,                    \
                (lds_void*)&BUF[w][r][1][0], 16, 0, 0);                       \
        }                                                                     \
    }

#define COMPUTE(BUF, t)                                                       \
    {                                                                         \
        _Pragma("unroll")                                                     \
        for (int r = 0; r < 4; ++r) {                                         \
            float4 a = BUF[w][r][0][lane];                                    \
            float4 b = BUF[w][r][1][lane];                                    \
            int n = n0 + (t) * 4 + r;                                         \
            if (n < n1) { ACC4(a, b); }                                       \
        }                                                                     \
    }

#define WAITV(N)                                                              \
    asm volatile("s_waitcnt vmcnt(" #N ")" ::: "memory");                     \
    __builtin_amdgcn_sched_barrier(0)

#define WAITL()                                                               \
    asm volatile("s_waitcnt lgkmcnt(0)" ::: "memory");                        \
    __builtin_amdgcn_sched_barrier(0)

    // T is even and >= 2 (host guarantees). Tiles 0..T-1, 4 rows each.
    ISSUE(BA, 0);
    ISSUE(BB, 1);
    for (int t = 0; t + 4 <= T; t += 2) {
        WAITV(8);                // tile t landed (t+1 still in flight)
        COMPUTE(BA, t);
        WAITL();                 // ds_reads of BA drained before overwrite
        ISSUE(BA, t + 2);
        WAITV(8);                // tile t+1 landed (t+2 in flight)
        COMPUTE(BB, t + 1);
        WAITL();
        ISSUE(BB, t + 3);
    }
    WAITV(8);
    COMPUTE(BA, T - 2);
    WAITV(0);
    COMPUTE(BB, T - 1);

#undef ACC4
#undef ISSUE
#undef COMPUTE
#undef WAITV
#undef WAITL

    // ws layout (float4 units): [4 kinds][NCHUNK][NCOL4]
    float4* SXX = ws;
    float4* SYY = ws + (size_t)NCHUNK * NCOL4;
    float4* SXY = ws + (size_t)2 * NCHUNK * NCOL4;
    float4* MX  = ws + (size_t)3 * NCHUNK * NCOL4;
    const size_t idx = (size_t)ch * NCOL4 + bx * 256 + tid;
    SXX[idx] = sxx;
    SYY[idx] = syy;
    SXY[idx] = sxy;
    MX[idx]  = mx;
}

// ---------------------------------------------------------------------------
// Phase 2 (fused final): combine chunks per column, nonlinearity + mask,
// per-block partial, then rocPRIM-style last-block reduction writes out[0].
// grid = 128 blocks x 256 threads; 16 cols x 16 chunk-strips (4 chunks each).
// ---------------------------------------------------------------------------
__global__ __launch_bounds__(256) void ncc_combine(const float4* __restrict__ ws4,
                                                   float* __restrict__ partials,
                                                   int* __restrict__ counter,
                                                   float* __restrict__ out) {
    const int c4l   = threadIdx.x & 15;          // 0..15 col within block
    const int strip = threadIdx.x >> 4;          // 0..15 chunk strip
    const int c4    = blockIdx.x * 16 + c4l;     // 0..2047

    const float4* SXX = ws4;
    const float4* SYY = ws4 + (size_t)NCHUNK * NCOL4;
    const float4* SXY = ws4 + (size_t)2 * NCHUNK * NCOL4;
    const float4* MX  = ws4 + (size_t)3 * NCHUNK * NCOL4;

    const int ch0 = strip * (NCHUNK / 16);       // 4 chunks per strip
    const int ch1 = ch0 + (NCHUNK / 16);

    float4 sxx = make_float4(0.f, 0.f, 0.f, 0.f);
    float4 syy = make_float4(0.f, 0.f, 0.f, 0.f);
    float4 sxy = make_float4(0.f, 0.f, 0.f, 0.f);
    float4 mx  = make_float4(0.f, 0.f, 0.f, 0.f);
    for (int ch = ch0; ch < ch1; ++ch) {
        const size_t idx = (size_t)ch * NCOL4 + c4;
        float4 a = SXX[idx], b = SYY[idx], d = SXY[idx], m = MX[idx];
        sxx.x += a.x; sxx.y += a.y; sxx.z += a.z; sxx.w += a.w;
        syy.x += b.x; syy.y += b.y; syy.z += b.z; syy.w += b.w;
        sxy.x += d.x; sxy.y += d.y; sxy.z += d.z; sxy.w += d.w;
        mx.x = fmaxf(mx.x, m.x); mx.y = fmaxf(mx.y, m.y);
        mx.z = fmaxf(mx.z, m.z); mx.w = fmaxf(mx.w, m.w);
    }

    __shared__ float4 L[16][4][16];
    L[strip][0][c4l] = sxx;
    L[strip][1][c4l] = syy;
    L[strip][2][c4l] = sxy;
    L[strip][3][c4l] = mx;
    __syncthreads();

    // tree reduce over strips: 16 -> 8 -> 4 -> 2 -> 1
    for (int s = 8; s >= 1; s >>= 1) {
        if (strip < s) {
            float4 a0 = L[strip][0][c4l], a1 = L[strip + s][0][c4l];
            float4 b0 = L[strip][1][c4l], b1 = L[strip + s][1][c4l];
            float4 d0 = L[strip][2][c4l], d1 = L[strip + s][2][c4l];
            float4 m0 = L[strip][3][c4l], m1 = L[strip + s][3][c4l];
            a0.x += a1.x; a0.y += a1.y; a0.z += a1.z; a0.w += a1.w;
            b0.x += b1.x; b0.y += b1.y; b0.z += b1.z; b0.w += b1.w;
            d0.x += d1.x; d0.y += d1.y; d0.z += d1.z; d0.w += d1.w;
            m0.x = fmaxf(m0.x, m1.x); m0.y = fmaxf(m0.y, m1.y);
            m0.z = fmaxf(m0.z, m1.z); m0.w = fmaxf(m0.w, m1.w);
            L[strip][0][c4l] = a0;
            L[strip][1][c4l] = b0;
            L[strip][2][c4l] = d0;
            L[strip][3][c4l] = m0;
        }
        __syncthreads();
    }

    if (strip == 0) {   // threads 0..15
        sxx = L[0][0][c4l];
        syy = L[0][1][c4l];
        sxy = L[0][2][c4l];
        mx  = L[0][3][c4l];
        float cc = 0.f;
        if (mx.x > 0.f) cc += -0.001f * sxy.x / ((sqrtf(sxx.x) + 1e-10f) * (sqrtf(syy.x) + 1e-10f));
        if (mx.y > 0.f) cc += -0.001f * sxy.y / ((sqrtf(sxx.y) + 1e-10f) * (sqrtf(syy.y) + 1e-10f));
        if (mx.z > 0.f) cc += -0.001f * sxy.z / ((sqrtf(sxx.z) + 1e-10f) * (sqrtf(syy.z) + 1e-10f));
        if (mx.w > 0.f) cc += -0.001f * sxy.w / ((sqrtf(sxx.w) + 1e-10f) * (sqrtf(syy.w) + 1e-10f));
        for (int off = 8; off > 0; off >>= 1)
            cc += __shfl_down(cc, off);
        if (c4l == 0)
            partials[blockIdx.x] = cc;
    }

    // --- fused final: last block to arrive sums the 128 partials ---
    __shared__ int lastFlag;
    if (threadIdx.x == 0) {
        __threadfence();   // release: partials[bid] visible device-wide
        int old = __hip_atomic_fetch_add(counter, 1, __ATOMIC_ACQ_REL,
                                         __HIP_MEMORY_SCOPE_AGENT);
        lastFlag = (old == NCBLK - 1);
    }
    __syncthreads();
    if (lastFlag) {
        float v = 0.f;
        if (threadIdx.x < NCBLK)
            v = __hip_atomic_load(&partials[threadIdx.x], __ATOMIC_RELAXED,
                                  __HIP_MEMORY_SCOPE_AGENT);
        for (int off = 32; off > 0; off >>= 1)
            v += __shfl_down(v, off);
        __shared__ float r[4];
        if ((threadIdx.x & 63) == 0) r[threadIdx.x >> 6] = v;
        __syncthreads();
        if (threadIdx.x == 0) out[0] = r[0] + r[1] + r[2] + r[3];
    }
}

extern "C" void kernel_launch(void* const* d_in, const int* in_sizes, int n_in,
                              void* d_out, int out_size, void* d_ws, size_t ws_size,
                              hipStream_t stream) {
    const float* x = (const float*)d_in[0];
    const float* y = (const float*)d_in[1];
    float* out = (float*)d_out;
    float* ws  = (float*)d_ws;

    // Workspace: 4 arrays * NCHUNK * NCOL floats (8.4 MB) + 128 partials + counter.
    const int clen = (NT + NCHUNK - 1) / NCHUNK;   // 79
    int T = (clen + 3) / 4;                        // 20 (even)
    if (T & 1) T++;
    if (T < 2) T = 2;

    float* partials = ws + 4ull * NCHUNK * NCOL;
    int*   counter  = (int*)(partials + NCBLK);

    dim3 g1(8, NCHUNK);
    ncc_partial<<<g1, 256, 0, stream>>>(x, y, (float4*)ws, counter, clen, T);
    ncc_combine<<<NCBLK, 256, 0, stream>>>((const float4*)ws, partials, counter, out);
}

// Round 9
// 63.512 us; speedup vs baseline: 1.0608x; 1.0608x over previous
//
#include <hip/hip_runtime.h>
#include <hip/hip_bf16.h>
#include <math.h>

// Problem: x, y fp32 [NT=5000, 512, 16] -> scalar
//   per column c (of 8192): sxx=sum x^2, syy=sum y^2, sxy=sum x*y, mx=max|x|
//   cc = -0.001*sxy/((sqrt(sxx)+1e-10)*(sqrt(syy)+1e-10)); out = sum(cc where mx>0)

#define NT       5000
#define NROW_F   8192          // floats per time row (512*16)
#define NCOL     8192
#define NCOL4    2048
#define NCHUNK   32            // 8 col-tiles * 32 = 256 blocks = 1/CU (R7 showed
                               // phase1 slightly FASTER than 2/CU, and halves ws)
#define NCBLK    128           // combine grid

typedef __attribute__((address_space(3))) void lds_void;
typedef const __attribute__((address_space(1))) void gm_void;

// ---------------------------------------------------------------------------
// Phase 1 (R4/R6-proven structure): wave-independent global_load_lds pipeline.
// grid = (8 col-tiles, 32 chunks); block = 256 (4 waves), LDS 64KB.
// Per 4-row tile: 8 x global_load_lds_dwordx4 (1KB each) fire-and-forget,
// counted s_waitcnt vmcnt(8) (never 0 mid-loop), ds_read_b128 consume.
// No __syncthreads in the loop. 4 waves/CU x ~16KB in flight = 64KB/CU >>
// ~9-22KB latency-BW product (R7 confirmed sufficient).
// ---------------------------------------------------------------------------
__global__ __launch_bounds__(256) void ncc_partial(const float* __restrict__ xg,
                                                   const float* __restrict__ yg,
                                                   float4* __restrict__ ws,
                                                   int clen, int T) {
    __shared__ float4 BA[4][4][2][64];
    __shared__ float4 BB[4][4][2][64];

    const int tid  = threadIdx.x;
    const int w    = tid >> 6;
    const int lane = tid & 63;
    const int bx   = blockIdx.x;        // 0..7 col-tile (1024 floats each)
    const int ch   = blockIdx.y;
    const int n0   = ch * clen;
    int n1 = n0 + clen; if (n1 > NT) n1 = NT;

    const int colf = bx * 1024 + tid * 4;   // first float column of this thread

    float4 sxx = make_float4(0.f, 0.f, 0.f, 0.f);
    float4 syy = make_float4(0.f, 0.f, 0.f, 0.f);
    float4 sxy = make_float4(0.f, 0.f, 0.f, 0.f);
    float4 mx  = make_float4(0.f, 0.f, 0.f, 0.f);

#define ACC4(a, b)                                                      \
    sxx.x = fmaf(a.x, a.x, sxx.x); sxx.y = fmaf(a.y, a.y, sxx.y);       \
    sxx.z = fmaf(a.z, a.z, sxx.z); sxx.w = fmaf(a.w, a.w, sxx.w);       \
    syy.x = fmaf(b.x, b.x, syy.x); syy.y = fmaf(b.y, b.y, syy.y);       \
    syy.z = fmaf(b.z, b.z, syy.z); syy.w = fmaf(b.w, b.w, syy.w);       \
    sxy.x = fmaf(a.x, b.x, sxy.x); sxy.y = fmaf(a.y, b.y, sxy.y);       \
    sxy.z = fmaf(a.z, b.z, sxy.z); sxy.w = fmaf(a.w, b.w, sxy.w);       \
    mx.x = fmaxf(mx.x, fabsf(a.x)); mx.y = fmaxf(mx.y, fabsf(a.y));     \
    mx.z = fmaxf(mx.z, fabsf(a.z)); mx.w = fmaxf(mx.w, fabsf(a.w))

#define ISSUE(BUF, t)                                                         \
    {                                                                         \
        _Pragma("unroll")                                                     \
        for (int r = 0; r < 4; ++r) {                                         \
            int n = n0 + (t) * 4 + r;                                         \
            if (n > NT - 1) n = NT - 1;                                       \
            const float* px = xg + (size_t)n * NROW_F + colf;                 \
            const float* py = yg + (size_t)n * NROW_F + colf;                 \
            __builtin_amdgcn_global_load_lds((gm_void*)px,                    \
                (lds_void*)&BUF[w][r][0][0], 16, 0, 0);                       \
            __builtin_amdgcn_global_load_lds((gm_void*)py,                    \
                (lds_void*)&BUF[w][r][1][0], 16, 0, 0);                       \
        }                                                                     \
    }

#define COMPUTE(BUF, t)                                                       \
    {                                                                         \
        _Pragma("unroll")                                                     \
        for (int r = 0; r < 4; ++r) {                                         \
            float4 a = BUF[w][r][0][lane];                                    \
            float4 b = BUF[w][r][1][lane];                                    \
            int n = n0 + (t) * 4 + r;                                         \
            if (n < n1) { ACC4(a, b); }                                       \
        }                                                                     \
    }

#define WAITV(N)                                                              \
    asm volatile("s_waitcnt vmcnt(" #N ")" ::: "memory");                     \
    __builtin_amdgcn_sched_barrier(0)

#define WAITL()                                                               \
    asm volatile("s_waitcnt lgkmcnt(0)" ::: "memory");                        \
    __builtin_amdgcn_sched_barrier(0)

    // T is even and >= 2 (host guarantees). Tiles 0..T-1, 4 rows each.
    ISSUE(BA, 0);
    ISSUE(BB, 1);
    for (int t = 0; t + 4 <= T; t += 2) {
        WAITV(8);                // tile t landed (t+1 still in flight)
        COMPUTE(BA, t);
        WAITL();                 // ds_reads of BA drained before overwrite
        ISSUE(BA, t + 2);
        WAITV(8);                // tile t+1 landed (t+2 in flight)
        COMPUTE(BB, t + 1);
        WAITL();
        ISSUE(BB, t + 3);
    }
    WAITV(8);
    COMPUTE(BA, T - 2);
    WAITV(0);
    COMPUTE(BB, T - 1);

#undef ACC4
#undef ISSUE
#undef COMPUTE
#undef WAITV
#undef WAITL

    // ws layout (float4 units): [4 kinds][NCHUNK][NCOL4]
    float4* SXX = ws;
    float4* SYY = ws + (size_t)NCHUNK * NCOL4;
    float4* SXY = ws + (size_t)2 * NCHUNK * NCOL4;
    float4* MX  = ws + (size_t)3 * NCHUNK * NCOL4;
    const size_t idx = (size_t)ch * NCOL4 + bx * 256 + tid;
    SXX[idx] = sxx;
    SYY[idx] = syy;
    SXY[idx] = sxy;
    MX[idx]  = mx;
}

// ---------------------------------------------------------------------------
// Phase 2 (R6-proven): combine chunks per column, nonlinearity + mask,
// one partial per block. grid = 128 blocks x 256 threads; 16 cols x 16
// chunk-strips (2 chunks each at NCHUNK=32); 4-round LDS tree.
// ---------------------------------------------------------------------------
__global__ __launch_bounds__(256) void ncc_combine(const float4* __restrict__ ws4,
                                                   float* __restrict__ partials) {
    const int c4l   = threadIdx.x & 15;          // 0..15 col within block
    const int strip = threadIdx.x >> 4;          // 0..15 chunk strip
    const int c4    = blockIdx.x * 16 + c4l;     // 0..2047

    const float4* SXX = ws4;
    const float4* SYY = ws4 + (size_t)NCHUNK * NCOL4;
    const float4* SXY = ws4 + (size_t)2 * NCHUNK * NCOL4;
    const float4* MX  = ws4 + (size_t)3 * NCHUNK * NCOL4;

    const int ch0 = strip * (NCHUNK / 16);       // 2 chunks per strip
    const int ch1 = ch0 + (NCHUNK / 16);

    float4 sxx = make_float4(0.f, 0.f, 0.f, 0.f);
    float4 syy = make_float4(0.f, 0.f, 0.f, 0.f);
    float4 sxy = make_float4(0.f, 0.f, 0.f, 0.f);
    float4 mx  = make_float4(0.f, 0.f, 0.f, 0.f);
    for (int ch = ch0; ch < ch1; ++ch) {
        const size_t idx = (size_t)ch * NCOL4 + c4;
        float4 a = SXX[idx], b = SYY[idx], d = SXY[idx], m = MX[idx];
        sxx.x += a.x; sxx.y += a.y; sxx.z += a.z; sxx.w += a.w;
        syy.x += b.x; syy.y += b.y; syy.z += b.z; syy.w += b.w;
        sxy.x += d.x; sxy.y += d.y; sxy.z += d.z; sxy.w += d.w;
        mx.x = fmaxf(mx.x, m.x); mx.y = fmaxf(mx.y, m.y);
        mx.z = fmaxf(mx.z, m.z); mx.w = fmaxf(mx.w, m.w);
    }

    __shared__ float4 L[16][4][16];
    L[strip][0][c4l] = sxx;
    L[strip][1][c4l] = syy;
    L[strip][2][c4l] = sxy;
    L[strip][3][c4l] = mx;
    __syncthreads();

    // tree reduce over strips: 16 -> 8 -> 4 -> 2 -> 1
    for (int s = 8; s >= 1; s >>= 1) {
        if (strip < s) {
            float4 a0 = L[strip][0][c4l], a1 = L[strip + s][0][c4l];
            float4 b0 = L[strip][1][c4l], b1 = L[strip + s][1][c4l];
            float4 d0 = L[strip][2][c4l], d1 = L[strip + s][2][c4l];
            float4 m0 = L[strip][3][c4l], m1 = L[strip + s][3][c4l];
            a0.x += a1.x; a0.y += a1.y; a0.z += a1.z; a0.w += a1.w;
            b0.x += b1.x; b0.y += b1.y; b0.z += b1.z; b0.w += b1.w;
            d0.x += d1.x; d0.y += d1.y; d0.z += d1.z; d0.w += d1.w;
            m0.x = fmaxf(m0.x, m1.x); m0.y = fmaxf(m0.y, m1.y);
            m0.z = fmaxf(m0.z, m1.z); m0.w = fmaxf(m0.w, m1.w);
            L[strip][0][c4l] = a0;
            L[strip][1][c4l] = b0;
            L[strip][2][c4l] = d0;
            L[strip][3][c4l] = m0;
        }
        __syncthreads();
    }

    if (strip == 0) {   // threads 0..15
        sxx = L[0][0][c4l];
        syy = L[0][1][c4l];
        sxy = L[0][2][c4l];
        mx  = L[0][3][c4l];
        float cc = 0.f;
        if (mx.x > 0.f) cc += -0.001f * sxy.x / ((sqrtf(sxx.x) + 1e-10f) * (sqrtf(syy.x) + 1e-10f));
        if (mx.y > 0.f) cc += -0.001f * sxy.y / ((sqrtf(sxx.y) + 1e-10f) * (sqrtf(syy.y) + 1e-10f));
        if (mx.z > 0.f) cc += -0.001f * sxy.z / ((sqrtf(sxx.z) + 1e-10f) * (sqrtf(syy.z) + 1e-10f));
        if (mx.w > 0.f) cc += -0.001f * sxy.w / ((sqrtf(sxx.w) + 1e-10f) * (sqrtf(syy.w) + 1e-10f));
        // reduce lanes 0..15 to lane 0 (lanes >=16 hold strip!=0 garbage that
        // never flows into lanes 0..15 with these offsets)
        for (int off = 8; off > 0; off >>= 1)
            cc += __shfl_down(cc, off);
        if (c4l == 0)
            partials[blockIdx.x] = cc;
    }
}

// Phase 3: sum 128 block partials -> scalar (2 waves).
__global__ __launch_bounds__(128) void ncc_final(const float* __restrict__ partials,
                                                 float* __restrict__ out) {
    float v = partials[threadIdx.x];
    for (int off = 32; off > 0; off >>= 1)
        v += __shfl_down(v, off);
    __shared__ float r[2];
    if ((threadIdx.x & 63) == 0) r[threadIdx.x >> 6] = v;
    __syncthreads();
    if (threadIdx.x == 0) out[0] = r[0] + r[1];
}

extern "C" void kernel_launch(void* const* d_in, const int* in_sizes, int n_in,
                              void* d_out, int out_size, void* d_ws, size_t ws_size,
                              hipStream_t stream) {
    const float* x = (const float*)d_in[0];
    const float* y = (const float*)d_in[1];
    float* out = (float*)d_out;
    float* ws  = (float*)d_ws;

    // Workspace: 4 arrays * NCHUNK * NCOL floats (4.2 MB) + 128 partials.
    const int clen = (NT + NCHUNK - 1) / NCHUNK;   // 157
    int T = (clen + 3) / 4;                        // 40 (even)
    if (T & 1) T++;
    if (T < 2) T = 2;

    float* partials = ws + 4ull * NCHUNK * NCOL;

    dim3 g1(8, NCHUNK);
    ncc_partial<<<g1, 256, 0, stream>>>(x, y, (float4*)ws, clen, T);
    ncc_combine<<<NCBLK, 256, 0, stream>>>((const float4*)ws, partials);
    ncc_final<<<1, 128, 0, stream>>>(partials, out);
}